// Round 15
// baseline (324.367 us; speedup 1.0000x reference)
//
#include <hip/hip_runtime.h>
#include <stdint.h>

#define D_ 256
#define NQ_ 512
#define NK_ 512
#define NP_ (NQ_*NK_)

typedef __attribute__((ext_vector_type(8))) __bf16 bf16x8;
typedef __attribute__((ext_vector_type(4))) float f32x4;

__device__ __forceinline__ unsigned short f2bf(float f) {
  unsigned u = __builtin_bit_cast(unsigned, f);
  u += 0x7FFFu + ((u >> 16) & 1u);   // RNE
  return (unsigned short)(u >> 16);
}
__device__ __forceinline__ unsigned pk2(float a, float b) {
  return (unsigned)f2bf(a) | ((unsigned)f2bf(b) << 16);
}
__device__ __forceinline__ unsigned encf(float f) {  // order-preserving float->uint
  unsigned u = __builtin_bit_cast(unsigned, f);
  return (u & 0x80000000u) ? ~u : (u | 0x80000000u);
}
__device__ __forceinline__ float decf(unsigned e) {
  unsigned u = (e & 0x80000000u) ? (e ^ 0x80000000u) : ~e;
  return __builtin_bit_cast(float, u);
}

// ---------------- shared GEMM body (direct-from-global MFMA) ----------------
template<int EPI, int KTILES>
__device__ __forceinline__ void gemm_body(
    const unsigned short* __restrict__ A, int lda,
    const unsigned short* __restrict__ B, int ldb,
    const float* __restrict__ bias,
    void* __restrict__ Dst, int ldd, int nTilesN, int bid) {
  const int t = threadIdx.x, w = t >> 6, l = t & 63, l15 = l & 15, g = l >> 4;
  const int bm = bid / nTilesN, bn = bid % nTilesN;
  const int m0 = bm*64 + w*16, n0 = bn*64;
  const unsigned short* Ap = A + (size_t)(m0 + l15)*lda + g*8;
  const unsigned short* Bp = B + (size_t)(n0 + l15)*ldb + g*8;
  f32x4 acc[4];
  #pragma unroll
  for (int n = 0; n < 4; ++n) acc[n] = (f32x4){0.f,0.f,0.f,0.f};
  #pragma unroll 2
  for (int kk = 0; kk < KTILES; ++kk) {
    bf16x8 a = *(const bf16x8*)(Ap + kk*32);
    #pragma unroll
    for (int n = 0; n < 4; ++n) {
      bf16x8 b = *(const bf16x8*)(Bp + (size_t)n*16*ldb + kk*32);
      acc[n] = __builtin_amdgcn_mfma_f32_16x16x32_bf16(a, b, acc[n], 0, 0, 0);
    }
  }
  #pragma unroll
  for (int n = 0; n < 4; ++n) {
    const int col = n0 + n*16 + l15;
    const float bc = (EPI & 4) ? bias[col] : 0.f;
    #pragma unroll
    for (int r = 0; r < 4; ++r) {
      const int m = m0 + g*4 + r;
      float v = acc[n][r] + bc;
      if (EPI & 8) v += bias[m];
      if (EPI & 2) v = fmaxf(v, 0.f);
      if (EPI & 1) ((unsigned short*)Dst)[(size_t)m*ldd + col] = f2bf(v);
      else         ((float*)Dst)[(size_t)m*ldd + col] = v;
    }
  }
}

template<int EPI, int KTILES>
__global__ __launch_bounds__(256) void gemm_k(
    const unsigned short* __restrict__ A, int lda,
    const unsigned short* __restrict__ B, int ldb,
    const float* __restrict__ bias,
    void* __restrict__ Dst, int ldd, int nTilesN) {
  gemm_body<EPI, KTILES>(A, lda, B, ldb, bias, Dst, ldd, nTilesN, blockIdx.x);
}

// ---------------- kprep: init + conversions (incl. frag-ordered Ab) + transposes ----
// blocks: 0 = init; [1,705) convert regions; [705,737) x->catT; [737,769) source->srcT
__global__ __launch_bounds__(256) void kprep(
    const unsigned* __restrict__ maskw, unsigned* __restrict__ wsMin,
    unsigned* __restrict__ wsFlag,
    const float* __restrict__ aW1, const float* __restrict__ source,
    const float* __restrict__ x, const float* __restrict__ mW1,
    const float* __restrict__ mW2,
    unsigned short* __restrict__ Ab, unsigned short* __restrict__ srcbf,
    unsigned short* __restrict__ mW1b, unsigned short* __restrict__ mW2b,
    unsigned short* __restrict__ aW1A, unsigned short* __restrict__ aW1B,
    unsigned short* __restrict__ catT, unsigned short* __restrict__ srcT) {
  __shared__ float tile[64][65];
  const int b = blockIdx.x, t = threadIdx.x;
  if (b == 0) {
    if (t < 64) {
      unsigned a01 = 1, af = 1;
      for (int i = 0; i < 4; ++i) {
        unsigned v = maskw[t*4 + i];
        a01 &= (v == 0u || v == 1u) ? 1u : 0u;
        af  &= (v == 0u || v == 0x3f800000u) ? 1u : 0u;
      }
      unsigned long long b01 = __ballot(a01 != 0), bf = __ballot(af != 0);
      if (t == 0) {
        *wsFlag = (b01 == ~0ull) ? 1u : ((bf == ~0ull) ? 2u : 0u);
        *wsMin = 0xFFFFFFFFu;
      }
    }
    return;
  }
  if (b < 705) {
    const int bb = b - 1;
    const float* src; unsigned short* dst;
    if (bb < 64) {
      // Ab: A-fragment-linear image of aW1[:,512:768] (validated r8).
      int j = bb*1024 + t*4;
      int img = j >> 9, li = (j >> 3) & 63, i0 = j & 7;
      int row = ((img >> 2) & 3)*64 + (img & 3)*16 + (li & 15);
      int ch  = (img >> 4)*32 + (li >> 4)*8 + i0;
      src = aW1 + row*768 + 512 + ch; dst = Ab + j;
    }
    else if (bb < 192)  { int j = (bb-64)*1024 + t*4;  src = source + j;    dst = srcbf + j; }
    else if (bb < 448)  { int j = (bb-192)*1024 + t*4; src = mW1 + j;       dst = mW1b + j; }
    else if (bb < 576)  { int j = (bb-448)*1024 + t*4; src = mW2 + j;       dst = mW2b + j; }
    else if (bb < 640)  { int j = (bb-576)*1024 + t*4; int e=j>>8, c=j&255; src = aW1 + e*768 + c;       dst = aW1A + j; }
    else                { int j = (bb-640)*1024 + t*4; int e=j>>8, c=j&255; src = aW1 + e*768 + 256 + c; dst = aW1B + j; }
    const float4 v = *(const float4*)src;
    ushort4 o; o.x=f2bf(v.x); o.y=f2bf(v.y); o.z=f2bf(v.z); o.w=f2bf(v.w);
    *(ushort4*)dst = o;
    return;
  }
  // tiled transpose f32 [256][512] -> bf16 [512][ldd]
  const float* src; unsigned short* dst; int ldd, bid;
  if (b < 737) { src = x;      dst = catT; ldd = 512; bid = b - 705; }
  else         { src = source; dst = srcT; ldd = 256; bid = b - 737; }
  const int bd = bid >> 3, bq = bid & 7;
  const int r = t >> 4, c4 = (t & 15) * 4;
  #pragma unroll
  for (int rr = 0; rr < 4; ++rr) {
    int dl = rr*16 + r;
    float4 v = *(const float4*)(src + (size_t)(bd*64 + dl)*512 + bq*64 + c4);
    tile[dl][c4+0] = v.x; tile[dl][c4+1] = v.y; tile[dl][c4+2] = v.z; tile[dl][c4+3] = v.w;
  }
  __syncthreads();
  #pragma unroll
  for (int rr = 0; rr < 4; ++rr) {
    int j = rr*16 + r;
    ushort4 o;
    o.x = f2bf(tile[c4+0][j]); o.y = f2bf(tile[c4+1][j]);
    o.z = f2bf(tile[c4+2][j]); o.w = f2bf(tile[c4+3][j]);
    *(ushort4*)(dst + (size_t)(bq*64 + j)*ldd + bd*64 + c4) = o;
  }
}

// ---------------- kprep2: Up and VmT GEMMs in one launch ----------------
__global__ __launch_bounds__(256) void kprep2(
    const unsigned short* __restrict__ catT, const unsigned short* __restrict__ aW1A,
    const float* __restrict__ ab1, float* __restrict__ Up,
    const unsigned short* __restrict__ srcT, const unsigned short* __restrict__ aW1B,
    float* __restrict__ VmT) {
  if (blockIdx.x < 32)
    gemm_body<4, 8>(catT, 512, aW1A, 256, ab1, (void*)Up, 256, 4, blockIdx.x);
  else
    gemm_body<0, 8>(srcT, 256, aW1B, 256, (const float*)nullptr, (void*)VmT, 256, 4, blockIdx.x - 32);
}

// ---------------- kscores3w helpers ----------------
// Thread quad set (fixed per wave-quarter wq): {2wq, 2wq+1, 2wq+4, 2wq+5}.
// Each load instr: one channel x 64 lanes = 256B contiguous; wave-pair halves adjacent.
__device__ __forceinline__ void loads16(float (&s)[16], const float* __restrict__ dbase,
                                        int kk, int wq) {
  #pragma unroll
  for (int qi = 0; qi < 4; ++qi) {
    const int quad = wq*2 + (qi & 1) + (qi >> 1)*4;
    #pragma unroll
    for (int i = 0; i < 4; ++i)
      s[qi*4 + i] = dbase[(size_t)(kk*32 + quad*4 + i) * NP_];
  }
}
// 2x b128 writes per thread, conflict-free; byte layout identical to r9 formula:
// quad q -> row l, chunk ((q>>1)^key)*16 + (q&1)*8 ; quads {2a,2a+1} share a chunk.
__device__ __forceinline__ void cvtwrite16(unsigned char* __restrict__ buf, const float (&s)[16],
                                           int l, int wq) {
  const int key = (l >> 1) & 3;
  {
    uint4 o;
    o.x = pk2(s[0], s[1]);  o.y = pk2(s[2], s[3]);    // quad 2wq   -> bytes 0-7
    o.z = pk2(s[4], s[5]);  o.w = pk2(s[6], s[7]);    // quad 2wq+1 -> bytes 8-15
    *(uint4*)(buf + l*64 + ((wq ^ key) << 4)) = o;
  }
  {
    uint4 o;
    o.x = pk2(s[8],  s[9]);  o.y = pk2(s[10], s[11]); // quad 2wq+4
    o.z = pk2(s[12], s[13]); o.w = pk2(s[14], s[15]); // quad 2wq+5
    *(uint4*)(buf + l*64 + (((wq + 2) ^ key) << 4)) = o;
  }
}
__device__ __forceinline__ void loadA(bf16x8 (&a)[4], const unsigned short* __restrict__ Ab,
                                      int kk, int w, int l) {
  #pragma unroll
  for (int m = 0; m < 4; ++m)
    a[m] = *(const bf16x8*)(Ab + ((kk*16 + w*4 + m) << 9) + l*8);
}

// ---------------- KB: wide-tile persistent fused scores GEMM ----------------
// 512 blocks (all resident, 2/CU, XCD-bijective), 4 tiles of 128 pairs each.
// Waves 0-1 stage pair-half 0, waves 2-3 half 1 -> 512B/channel-visit (vs r9's 256B).
// Ring depth-2 (16 f32/slot); raw barriers + lgkmcnt only; acc init = Up.
// NOTE: (256,2) required — tighter VGPR caps spill the staging ring (r13: 311us).
__global__ __launch_bounds__(256, 2) void kscores3w(
    const float* __restrict__ dist, const unsigned short* __restrict__ Ab,
    const float* __restrict__ VmT, const float* __restrict__ Up,
    const float* __restrict__ aW2, const float* __restrict__ ab2,
    float* __restrict__ outScores, unsigned* __restrict__ wsMin) {
  __shared__ __align__(16) unsigned char ldsB[2][2][4096];  // [buf][half][64row x 64B]
  __shared__ float red[4][128];

  const int t = threadIdx.x, w = t >> 6, l = t & 63, l15 = l & 15, g = l >> 4;
  const int half = w >> 1, wq = w & 1;
  const int bs = (blockIdx.x & 7) * 64 + (blockIdx.x >> 3);  // XCD-bijective 0..511
  const int base_pair = bs * 512;

  // aW2 frag values: e = w*64 + m*16 + g*4 + r
  float aw[4][4];
  #pragma unroll
  for (int m = 0; m < 4; ++m) {
    const float4 v = *(const float4*)(aW2 + w*64 + m*16 + g*4);
    aw[m][0]=v.x; aw[m][1]=v.y; aw[m][2]=v.z; aw[m][3]=v.w;
  }
  const float ab2v = ab2[0];

  // prologue: ring slots 0,1 <- tile0 steps 0,1
  float s[2][16];
  {
    const float* db0 = dist + (size_t)base_pair + half*64 + l;
    loads16(s[0], db0, 0, wq);
    loads16(s[1], db0, 1, wq);
  }

  for (int tt = 0; tt < 4; ++tt) {
    const int p0 = base_pair + tt*128;
    const int q  = p0 >> 9;
    const int k0 = p0 & 511;
    const float* dbase = dist + (size_t)p0 + half*64 + l;

    // acc init = Up[q][e]  (broadcast over n)
    f32x4 acc[4][8];
    #pragma unroll
    for (int m = 0; m < 4; ++m) {
      const float4 u = *(const float4*)(Up + q*256 + w*64 + m*16 + g*4);
      #pragma unroll
      for (int n = 0; n < 8; ++n) {
        acc[m][n][0]=u.x; acc[m][n][1]=u.y; acc[m][n][2]=u.z; acc[m][n][3]=u.w;
      }
    }

    #pragma unroll
    for (int kk = 0; kk < 8; ++kk) {
      const int bb = kk & 1;
      cvtwrite16(&ldsB[bb][half][0], s[kk & 1], l, wq);
      if (kk < 6)      loads16(s[kk & 1], dbase, kk + 2, wq);
      else if (tt < 3) loads16(s[kk & 1], dbase + 128, kk - 6, wq);   // next tile 0,1
      bf16x8 af[4];
      loadA(af, Ab, kk, w, l);                       // L2-hot; latency hides under barrier
      __builtin_amdgcn_sched_barrier(0);
      asm volatile("s_waitcnt lgkmcnt(0)" ::: "memory");
      __builtin_amdgcn_s_barrier();                  // raw: no vmcnt drain
      __builtin_amdgcn_sched_barrier(0);
      bf16x8 bfrag[8];
      #pragma unroll
      for (int n = 0; n < 8; ++n) {
        const int pl = (n & 3)*16 + l15;
        const unsigned char* base = &ldsB[bb][n >> 2][0];
        bfrag[n] = *(const bf16x8*)(base + pl*64 + ((g ^ ((pl >> 1) & 3)) << 4));
      }
      #pragma unroll
      for (int m = 0; m < 4; ++m)
        #pragma unroll
        for (int n = 0; n < 8; ++n)
          acc[m][n] = __builtin_amdgcn_mfma_f32_16x16x32_bf16(af[m], bfrag[n], acc[m][n], 0, 0, 0);
    }

    // ---- epilogue: score[j] = ab2 + sum_e aW2[e]*relu(acc + VmT[j][e])
    float part[8];
    #pragma unroll
    for (int n = 0; n < 8; ++n) {
      const int j = k0 + n*16 + l15;
      float s2 = 0.f;
      #pragma unroll
      for (int m = 0; m < 4; ++m) {
        const float4 v4 = *(const float4*)(VmT + (size_t)j*256 + w*64 + m*16 + g*4);
        s2 += aw[m][0] * fmaxf(acc[m][n][0] + v4.x, 0.f);
        s2 += aw[m][1] * fmaxf(acc[m][n][1] + v4.y, 0.f);
        s2 += aw[m][2] * fmaxf(acc[m][n][2] + v4.z, 0.f);
        s2 += aw[m][3] * fmaxf(acc[m][n][3] + v4.w, 0.f);
      }
      s2 += __shfl_xor(s2, 16);
      s2 += __shfl_xor(s2, 32);
      part[n] = s2;
    }
    __builtin_amdgcn_s_barrier();          // red free (prev tile readers done)
    if (l < 16) {
      #pragma unroll
      for (int n = 0; n < 8; ++n) red[w][n*16 + l] = part[n];
    }
    asm volatile("s_waitcnt lgkmcnt(0)" ::: "memory");
    __builtin_amdgcn_s_barrier();
    if (t < 128) {
      float s2 = red[0][t] + red[1][t] + red[2][t] + red[3][t] + ab2v;
      outScores[p0 + t] = s2;
      float mn = s2;
      #pragma unroll
      for (int off = 32; off; off >>= 1) mn = fminf(mn, __shfl_xor(mn, off));
      if (l == 0) atomicMin(wsMin, encf(mn));
    }
  }
}

// ---------------- KS: mask + softmax -> masked scores (out) + prob bf16 ----------------
__global__ __launch_bounds__(256) void ksoftmax(
    const void* __restrict__ maskp,
    const unsigned* __restrict__ wsMin, const unsigned* __restrict__ wsFlag,
    float* __restrict__ scores, unsigned short* __restrict__ prob) {
  __shared__ float srow[512];
  __shared__ float redl[8];
  const int t = threadIdx.x, w = t >> 6, l = t & 63;
  const int q = blockIdx.x;
  const float neg = decf(*wsMin) - 20.0f;
  const unsigned flag = *wsFlag;

  for (int k = t; k < 512; k += 256) {
    float raw = scores[q*512 + k];
    bool mv;
    if (flag == 1)      mv = ((const int*)maskp)[q*512 + k] != 0;
    else if (flag == 2) mv = ((const float*)maskp)[q*512 + k] != 0.f;
    else                mv = ((const unsigned char*)maskp)[q*512 + k] != 0;
    float ms = raw + (mv ? 0.f : neg);
    scores[q*512 + k] = ms;
    srow[k] = ms;
  }
  __syncthreads();
  float lm = fmaxf(srow[t], srow[t + 256]);
  #pragma unroll
  for (int off = 32; off; off >>= 1) lm = fmaxf(lm, __shfl_xor(lm, off));
  if (l == 0) redl[w] = lm;
  __syncthreads();
  float rmax = fmaxf(fmaxf(redl[0], redl[1]), fmaxf(redl[2], redl[3]));
  float e0 = __expf(srow[t] - rmax), e1 = __expf(srow[t + 256] - rmax);
  float ls = e0 + e1;
  #pragma unroll
  for (int off = 32; off; off >>= 1) ls += __shfl_xor(ls, off);
  if (l == 0) redl[4 + w] = ls;
  __syncthreads();
  float inv = 1.0f / (redl[4] + redl[5] + redl[6] + redl[7]);
  prob[q*512 + t]       = f2bf(e0 * inv);
  prob[q*512 + t + 256] = f2bf(e1 * inv);
}

extern "C" void kernel_launch(void* const* d_in, const int* in_sizes, int n_in,
                              void* d_out, int out_size, void* d_ws, size_t ws_size,
                              hipStream_t stream) {
  const float* x      = (const float*)d_in[0];
  const float* source = (const float*)d_in[1];
  const float* dist   = (const float*)d_in[2];
  const void*  mask   = (const void*)d_in[3];
  const float* aW1    = (const float*)d_in[4];
  const float* ab1    = (const float*)d_in[5];
  const float* aW2    = (const float*)d_in[6];
  const float* ab2    = (const float*)d_in[7];
  const float* mW1    = (const float*)d_in[8];
  const float* mb1    = (const float*)d_in[9];
  const float* mW2    = (const float*)d_in[10];
  const float* mb2    = (const float*)d_in[11];

  float* outMain = (float*)d_out;             // (1,256,512)
  float* scores  = outMain + 256*512;         // (1,512,512)

  char* ws = (char*)d_ws;
  unsigned* wsMin  = (unsigned*)ws;
  unsigned* wsFlag = wsMin + 1;
  unsigned short* Ab    = (unsigned short*)(ws + 1024);     // 128KB A frag-linear
  float*          Up    = (float*)(ws + 132096);            // 512x256 f32
  float*          VmT   = (float*)(ws + 656384);            // 512x256 f32 [k][e]
  unsigned short* srcbf = (unsigned short*)(ws + 1180672);  // 256x512 bf16 [d][k]
  unsigned short* srcT  = (unsigned short*)(ws + 1442816);  // 512x256 bf16 [k][c]
  unsigned short* mW1b  = (unsigned short*)(ws + 1704960);  // 512x512 bf16
  unsigned short* mW2b  = (unsigned short*)(ws + 2229248);  // 256x512 bf16
  unsigned short* aW1A  = (unsigned short*)(ws + 2491392);  // 256x256 bf16
  unsigned short* aW1B  = (unsigned short*)(ws + 2622464);  // 256x256 bf16
  unsigned short* catT  = (unsigned short*)(ws + 2753536);  // 512x512 bf16 [q][c]
  unsigned short* prob  = (unsigned short*)(ws + 3277824);  // 512x512 bf16 [q][k]
  unsigned short* h2T   = (unsigned short*)(ws + 3802112);  // 512x512 bf16 [q][o]

  hipLaunchKernelGGL(kprep, dim3(769), dim3(256), 0, stream,
                     (const unsigned*)mask, wsMin, wsFlag, aW1, source, x, mW1, mW2,
                     Ab, srcbf, mW1b, mW2b, aW1A, aW1B, catT, srcT);
  hipLaunchKernelGGL(kprep2, dim3(64), dim3(256), 0, stream,
                     catT, aW1A, ab1, Up, srcT, aW1B, VmT);
  hipLaunchKernelGGL(kscores3w, dim3(512), dim3(256), 0, stream,
                     dist, Ab, VmT, Up, aW2, ab2, scores, wsMin);
  hipLaunchKernelGGL(ksoftmax, dim3(512), dim3(256), 0, stream,
                     mask, wsMin, wsFlag, scores, prob);
  // msgT[q][d] = prob @ source^T  -> catT[:, 256:]
  hipLaunchKernelGGL((gemm_k<1, 16>), dim3(32), dim3(256), 0, stream,
                     prob, 512, srcbf, 512, (const float*)nullptr, (void*)(catT + 256), 512, 4);
  // h2T[q][o] = relu(catT @ mW1^T + mb1)
  hipLaunchKernelGGL((gemm_k<7, 16>), dim3(64), dim3(256), 0, stream,
                     catT, 512, mW1b, 512, mb1, (void*)h2T, 512, 8);
  // out[o2][q] = mW2 @ h2 + mb2
  hipLaunchKernelGGL((gemm_k<8, 16>), dim3(32), dim3(256), 0, stream,
                     mW2b, 512, h2T, 512, mb2, (void*)outMain, 512, 8);
}

// Round 16
// 167.015 us; speedup vs baseline: 1.9421x; 1.9421x over previous
//
#include <hip/hip_runtime.h>
#include <stdint.h>

#define D_ 256
#define NQ_ 512
#define NK_ 512
#define NP_ (NQ_*NK_)

typedef __attribute__((ext_vector_type(8))) __bf16 bf16x8;
typedef __attribute__((ext_vector_type(4))) float f32x4;

__device__ __forceinline__ unsigned short f2bf(float f) {
  unsigned u = __builtin_bit_cast(unsigned, f);
  u += 0x7FFFu + ((u >> 16) & 1u);   // RNE
  return (unsigned short)(u >> 16);
}
__device__ __forceinline__ unsigned encf(float f) {  // order-preserving float->uint
  unsigned u = __builtin_bit_cast(unsigned, f);
  return (u & 0x80000000u) ? ~u : (u | 0x80000000u);
}
__device__ __forceinline__ float decf(unsigned e) {
  unsigned u = (e & 0x80000000u) ? (e ^ 0x80000000u) : ~e;
  return __builtin_bit_cast(float, u);
}

// ---------------- shared GEMM body (direct-from-global MFMA) ----------------
template<int EPI, int KTILES>
__device__ __forceinline__ void gemm_body(
    const unsigned short* __restrict__ A, int lda,
    const unsigned short* __restrict__ B, int ldb,
    const float* __restrict__ bias,
    void* __restrict__ Dst, int ldd, int nTilesN, int bid) {
  const int t = threadIdx.x, w = t >> 6, l = t & 63, l15 = l & 15, g = l >> 4;
  const int bm = bid / nTilesN, bn = bid % nTilesN;
  const int m0 = bm*64 + w*16, n0 = bn*64;
  const unsigned short* Ap = A + (size_t)(m0 + l15)*lda + g*8;
  const unsigned short* Bp = B + (size_t)(n0 + l15)*ldb + g*8;
  f32x4 acc[4];
  #pragma unroll
  for (int n = 0; n < 4; ++n) acc[n] = (f32x4){0.f,0.f,0.f,0.f};
  #pragma unroll 2
  for (int kk = 0; kk < KTILES; ++kk) {
    bf16x8 a = *(const bf16x8*)(Ap + kk*32);
    #pragma unroll
    for (int n = 0; n < 4; ++n) {
      bf16x8 b = *(const bf16x8*)(Bp + (size_t)n*16*ldb + kk*32);
      acc[n] = __builtin_amdgcn_mfma_f32_16x16x32_bf16(a, b, acc[n], 0, 0, 0);
    }
  }
  #pragma unroll
  for (int n = 0; n < 4; ++n) {
    const int col = n0 + n*16 + l15;
    const float bc = (EPI & 4) ? bias[col] : 0.f;
    #pragma unroll
    for (int r = 0; r < 4; ++r) {
      const int m = m0 + g*4 + r;
      float v = acc[n][r] + bc;
      if (EPI & 8) v += bias[m];
      if (EPI & 2) v = fmaxf(v, 0.f);
      if (EPI & 1) ((unsigned short*)Dst)[(size_t)m*ldd + col] = f2bf(v);
      else         ((float*)Dst)[(size_t)m*ldd + col] = v;
    }
  }
}

template<int EPI, int KTILES>
__global__ __launch_bounds__(256) void gemm_k(
    const unsigned short* __restrict__ A, int lda,
    const unsigned short* __restrict__ B, int ldb,
    const float* __restrict__ bias,
    void* __restrict__ Dst, int ldd, int nTilesN) {
  gemm_body<EPI, KTILES>(A, lda, B, ldb, bias, Dst, ldd, nTilesN, blockIdx.x);
}

// ---------------- kprep: init + conversions (incl. frag-ordered Ab) + transposes ----
// blocks: 0 = init; [1,705) convert regions; [705,737) x->catT; [737,769) source->srcT
__global__ __launch_bounds__(256) void kprep(
    const unsigned* __restrict__ maskw, unsigned* __restrict__ wsMin,
    unsigned* __restrict__ wsFlag,
    const float* __restrict__ aW1, const float* __restrict__ source,
    const float* __restrict__ x, const float* __restrict__ mW1,
    const float* __restrict__ mW2,
    unsigned short* __restrict__ Ab, unsigned short* __restrict__ srcbf,
    unsigned short* __restrict__ mW1b, unsigned short* __restrict__ mW2b,
    unsigned short* __restrict__ aW1A, unsigned short* __restrict__ aW1B,
    unsigned short* __restrict__ catT, unsigned short* __restrict__ srcT) {
  __shared__ float tile[64][65];
  const int b = blockIdx.x, t = threadIdx.x;
  if (b == 0) {
    if (t < 64) {
      unsigned a01 = 1, af = 1;
      for (int i = 0; i < 4; ++i) {
        unsigned v = maskw[t*4 + i];
        a01 &= (v == 0u || v == 1u) ? 1u : 0u;
        af  &= (v == 0u || v == 0x3f800000u) ? 1u : 0u;
      }
      unsigned long long b01 = __ballot(a01 != 0), bf = __ballot(af != 0);
      if (t == 0) {
        *wsFlag = (b01 == ~0ull) ? 1u : ((bf == ~0ull) ? 2u : 0u);
        *wsMin = 0xFFFFFFFFu;
      }
    }
    return;
  }
  if (b < 705) {
    const int bb = b - 1;
    const float* src; unsigned short* dst;
    if (bb < 64) {
      // Ab: A-fragment-linear image of aW1[:,512:768] (validated r8).
      int j = bb*1024 + t*4;
      int img = j >> 9, li = (j >> 3) & 63, i0 = j & 7;
      int row = ((img >> 2) & 3)*64 + (img & 3)*16 + (li & 15);
      int ch  = (img >> 4)*32 + (li >> 4)*8 + i0;
      src = aW1 + row*768 + 512 + ch; dst = Ab + j;
    }
    else if (bb < 192)  { int j = (bb-64)*1024 + t*4;  src = source + j;    dst = srcbf + j; }
    else if (bb < 448)  { int j = (bb-192)*1024 + t*4; src = mW1 + j;       dst = mW1b + j; }
    else if (bb < 576)  { int j = (bb-448)*1024 + t*4; src = mW2 + j;       dst = mW2b + j; }
    else if (bb < 640)  { int j = (bb-576)*1024 + t*4; int e=j>>8, c=j&255; src = aW1 + e*768 + c;       dst = aW1A + j; }
    else                { int j = (bb-640)*1024 + t*4; int e=j>>8, c=j&255; src = aW1 + e*768 + 256 + c; dst = aW1B + j; }
    const float4 v = *(const float4*)src;
    ushort4 o; o.x=f2bf(v.x); o.y=f2bf(v.y); o.z=f2bf(v.z); o.w=f2bf(v.w);
    *(ushort4*)dst = o;
    return;
  }
  // tiled transpose f32 [256][512] -> bf16 [512][ldd]
  const float* src; unsigned short* dst; int ldd, bid;
  if (b < 737) { src = x;      dst = catT; ldd = 512; bid = b - 705; }
  else         { src = source; dst = srcT; ldd = 256; bid = b - 737; }
  const int bd = bid >> 3, bq = bid & 7;
  const int r = t >> 4, c4 = (t & 15) * 4;
  #pragma unroll
  for (int rr = 0; rr < 4; ++rr) {
    int dl = rr*16 + r;
    float4 v = *(const float4*)(src + (size_t)(bd*64 + dl)*512 + bq*64 + c4);
    tile[dl][c4+0] = v.x; tile[dl][c4+1] = v.y; tile[dl][c4+2] = v.z; tile[dl][c4+3] = v.w;
  }
  __syncthreads();
  #pragma unroll
  for (int rr = 0; rr < 4; ++rr) {
    int j = rr*16 + r;
    ushort4 o;
    o.x = f2bf(tile[c4+0][j]); o.y = f2bf(tile[c4+1][j]);
    o.z = f2bf(tile[c4+2][j]); o.w = f2bf(tile[c4+3][j]);
    *(ushort4*)(dst + (size_t)(bq*64 + j)*ldd + bd*64 + c4) = o;
  }
}

// ---------------- kprep2: Up and VmT GEMMs in one launch ----------------
// Up[q][e] = xT@aW1A + ab1 ; VmT[k][e] = srcT@aW1B^T  (V transposed for vec epilogue)
__global__ __launch_bounds__(256) void kprep2(
    const unsigned short* __restrict__ catT, const unsigned short* __restrict__ aW1A,
    const float* __restrict__ ab1, float* __restrict__ Up,
    const unsigned short* __restrict__ srcT, const unsigned short* __restrict__ aW1B,
    float* __restrict__ VmT) {
  if (blockIdx.x < 32)
    gemm_body<4, 8>(catT, 512, aW1A, 256, ab1, (void*)Up, 256, 4, blockIdx.x);
  else
    gemm_body<0, 8>(srcT, 256, aW1B, 256, (const float*)nullptr, (void*)VmT, 256, 4, blockIdx.x - 32);
}

// ---------------- kscores helpers ----------------
__device__ __forceinline__ void loads8(float (&s)[8], const float* __restrict__ dbase,
                                       int kk, int quad1, int quad2) {
  #pragma unroll
  for (int i = 0; i < 4; ++i) s[i]   = dbase[(size_t)(kk*32 + quad1*4 + i) * NP_];
  #pragma unroll
  for (int i = 0; i < 4; ++i) s[4+i] = dbase[(size_t)(kk*32 + quad2*4 + i) * NP_];
}
__device__ __forceinline__ void cvtwrite(unsigned char* __restrict__ buf, const float (&s)[8],
                                         int l, int quad1, int quad2) {
  const int key = (l >> 1) & 3;
  {
    unsigned lo = (unsigned)f2bf(s[0]) | ((unsigned)f2bf(s[1]) << 16);
    unsigned hi = (unsigned)f2bf(s[2]) | ((unsigned)f2bf(s[3]) << 16);
    *(uint2*)(buf + l*64 + ((((quad1>>1) ^ key) << 4) | ((quad1 & 1) << 3))) = make_uint2(lo, hi);
  }
  {
    unsigned lo = (unsigned)f2bf(s[4]) | ((unsigned)f2bf(s[5]) << 16);
    unsigned hi = (unsigned)f2bf(s[6]) | ((unsigned)f2bf(s[7]) << 16);
    *(uint2*)(buf + l*64 + ((((quad2>>1) ^ key) << 4) | ((quad2 & 1) << 3))) = make_uint2(lo, hi);
  }
}
__device__ __forceinline__ void loadA(bf16x8 (&a)[4], const unsigned short* __restrict__ Ab,
                                      int kk, int w, int l) {
  #pragma unroll
  for (int m = 0; m < 4; ++m)
    a[m] = *(const bf16x8*)(Ab + ((kk*16 + w*4 + m) << 9) + l*8);
}
__device__ __forceinline__ void computeStep(f32x4 (&acc)[4][4], const bf16x8 (&a)[4],
                                            const unsigned char* __restrict__ buf,
                                            int l15, int g) {
  bf16x8 bfrag[4];
  #pragma unroll
  for (int n = 0; n < 4; ++n) {
    const int p = n*16 + l15;
    bfrag[n] = *(const bf16x8*)(buf + p*64 + ((g ^ ((p >> 1) & 3)) << 4));
  }
  #pragma unroll
  for (int m = 0; m < 4; ++m)
    #pragma unroll
    for (int n = 0; n < 4; ++n)
      acc[m][n] = __builtin_amdgcn_mfma_f32_16x16x32_bf16(a[m], bfrag[n], acc[m][n], 0, 0, 0);
}

// ---------------- KB: persistent fused scores GEMM (4 tiles/block, r9 config) ----------------
// 1024 blocks (XCD-bijective), each streams 4 consecutive 64-pair tiles (1KB/dist-row).
// Depth-4 register staging ring crosses tile boundaries; raw barriers + lgkmcnt only
// (zero vmcnt drains). acc init = Up; epilogue: VmT float4 + reg-resident aW2 dot.
// NOTE: (256,2) is required — any tighter VGPR cap spills the staging ring (r13: 311us).
__global__ __launch_bounds__(256, 2) void kscores3(
    const float* __restrict__ dist, const unsigned short* __restrict__ Ab,
    const float* __restrict__ VmT, const float* __restrict__ Up,
    const float* __restrict__ aW2, const float* __restrict__ ab2,
    float* __restrict__ outScores, unsigned* __restrict__ wsMin) {
  __shared__ __align__(16) unsigned char ldsB[2][4096];
  __shared__ float red[4][64];

  const int t = threadIdx.x, w = t >> 6, l = t & 63, l15 = l & 15, g = l >> 4;
  const int bs = (blockIdx.x & 7) * 128 + (blockIdx.x >> 3);  // XCD-bijective
  const int base_tile = bs * 4;

  const int quad1 = (w + g) & 3;
  const int quad2 = quad1 + 4;

  // aW2 frag values (constant across tiles): e = w*64 + m*16 + g*4 + r
  float aw[4][4];
  #pragma unroll
  for (int m = 0; m < 4; ++m) {
    const float4 v = *(const float4*)(aW2 + w*64 + m*16 + g*4);
    aw[m][0]=v.x; aw[m][1]=v.y; aw[m][2]=v.z; aw[m][3]=v.w;
  }
  const float ab2v = ab2[0];

  // prologue: fill staging slots 0..2 with tile0 steps 0..2
  float s[4][8];
  {
    const float* db0 = dist + (size_t)base_tile*64 + l;
    loads8(s[0], db0, 0, quad1, quad2);
    loads8(s[1], db0, 1, quad1, quad2);
    loads8(s[2], db0, 2, quad1, quad2);
  }

  for (int tt = 0; tt < 4; ++tt) {
    const int p0 = (base_tile + tt) * 64;
    const int q  = p0 >> 9;
    const int k0 = p0 & 511;
    const float* dbase = dist + (size_t)p0 + l;

    // acc init = Up[q][e]  (broadcast over n)
    f32x4 acc[4][4];
    #pragma unroll
    for (int m = 0; m < 4; ++m) {
      const float4 u = *(const float4*)(Up + q*256 + w*64 + m*16 + g*4);
      #pragma unroll
      for (int n = 0; n < 4; ++n) {
        acc[m][n][0]=u.x; acc[m][n][1]=u.y; acc[m][n][2]=u.z; acc[m][n][3]=u.w;
      }
    }

    bf16x8 af[2][4];
    loadA(af[0], Ab, 0, w, l);

    #pragma unroll
    for (int kk = 0; kk < 8; ++kk) {
      const int bb = kk & 1;
      cvtwrite(ldsB[bb], s[kk & 3], l, quad1, quad2);
      if (kk < 5) {
        loads8(s[(kk + 3) & 3], dbase, kk + 3, quad1, quad2);
      } else if (tt < 3) {
        loads8(s[(kk + 3) & 3], dbase + 64, kk - 5, quad1, quad2);  // next tile 0..2
      }
      __builtin_amdgcn_sched_barrier(0);
      asm volatile("s_waitcnt lgkmcnt(0)" ::: "memory");
      __builtin_amdgcn_s_barrier();                     // raw: no vmcnt drain
      __builtin_amdgcn_sched_barrier(0);
      if (kk < 7) loadA(af[(kk + 1) & 1], Ab, kk + 1, w, l);
      computeStep(acc, af[kk & 1], ldsB[bb], l15, g);
    }

    // ---- epilogue: score[j] = ab2 + sum_e aW2[e]*relu(acc + VmT[j][e])
    float part[4];
    #pragma unroll
    for (int n = 0; n < 4; ++n) {
      const int j = k0 + n*16 + l15;
      float s2 = 0.f;
      #pragma unroll
      for (int m = 0; m < 4; ++m) {
        const float4 v4 = *(const float4*)(VmT + (size_t)j*256 + w*64 + m*16 + g*4);
        s2 += aw[m][0] * fmaxf(acc[m][n][0] + v4.x, 0.f);
        s2 += aw[m][1] * fmaxf(acc[m][n][1] + v4.y, 0.f);
        s2 += aw[m][2] * fmaxf(acc[m][n][2] + v4.z, 0.f);
        s2 += aw[m][3] * fmaxf(acc[m][n][3] + v4.w, 0.f);
      }
      s2 += __shfl_xor(s2, 16);
      s2 += __shfl_xor(s2, 32);
      part[n] = s2;
    }
    __builtin_amdgcn_s_barrier();          // red free (prev tile readers done)
    if (l < 16) {
      #pragma unroll
      for (int n = 0; n < 4; ++n) red[w][n*16 + l] = part[n];
    }
    asm volatile("s_waitcnt lgkmcnt(0)" ::: "memory");
    __builtin_amdgcn_s_barrier();
    if (t < 64) {
      float s2 = red[0][t] + red[1][t] + red[2][t] + red[3][t] + ab2v;
      outScores[p0 + t] = s2;
      float mn = s2;
      #pragma unroll
      for (int off = 32; off; off >>= 1) mn = fminf(mn, __shfl_xor(mn, off));
      if (t == 0) atomicMin(wsMin, encf(mn));
    }
  }
}

// ---------------- KS: mask + softmax -> masked scores (out) + prob bf16 ----------------
__global__ __launch_bounds__(256) void ksoftmax(
    const void* __restrict__ maskp,
    const unsigned* __restrict__ wsMin, const unsigned* __restrict__ wsFlag,
    float* __restrict__ scores, unsigned short* __restrict__ prob) {
  __shared__ float srow[512];
  __shared__ float redl[8];
  const int t = threadIdx.x, w = t >> 6, l = t & 63;
  const int q = blockIdx.x;
  const float neg = decf(*wsMin) - 20.0f;
  const unsigned flag = *wsFlag;

  for (int k = t; k < 512; k += 256) {
    float raw = scores[q*512 + k];
    bool mv;
    if (flag == 1)      mv = ((const int*)maskp)[q*512 + k] != 0;
    else if (flag == 2) mv = ((const float*)maskp)[q*512 + k] != 0.f;
    else                mv = ((const unsigned char*)maskp)[q*512 + k] != 0;
    float ms = raw + (mv ? 0.f : neg);
    scores[q*512 + k] = ms;
    srow[k] = ms;
  }
  __syncthreads();
  float lm = fmaxf(srow[t], srow[t + 256]);
  #pragma unroll
  for (int off = 32; off; off >>= 1) lm = fmaxf(lm, __shfl_xor(lm, off));
  if (l == 0) redl[w] = lm;
  __syncthreads();
  float rmax = fmaxf(fmaxf(redl[0], redl[1]), fmaxf(redl[2], redl[3]));
  float e0 = __expf(srow[t] - rmax), e1 = __expf(srow[t + 256] - rmax);
  float ls = e0 + e1;
  #pragma unroll
  for (int off = 32; off; off >>= 1) ls += __shfl_xor(ls, off);
  if (l == 0) redl[4 + w] = ls;
  __syncthreads();
  float inv = 1.0f / (redl[4] + redl[5] + redl[6] + redl[7]);
  prob[q*512 + t]       = f2bf(e0 * inv);
  prob[q*512 + t + 256] = f2bf(e1 * inv);
}

extern "C" void kernel_launch(void* const* d_in, const int* in_sizes, int n_in,
                              void* d_out, int out_size, void* d_ws, size_t ws_size,
                              hipStream_t stream) {
  const float* x      = (const float*)d_in[0];
  const float* source = (const float*)d_in[1];
  const float* dist   = (const float*)d_in[2];
  const void*  mask   = (const void*)d_in[3];
  const float* aW1    = (const float*)d_in[4];
  const float* ab1    = (const float*)d_in[5];
  const float* aW2    = (const float*)d_in[6];
  const float* ab2    = (const float*)d_in[7];
  const float* mW1    = (const float*)d_in[8];
  const float* mb1    = (const float*)d_in[9];
  const float* mW2    = (const float*)d_in[10];
  const float* mb2    = (const float*)d_in[11];

  float* outMain = (float*)d_out;             // (1,256,512)
  float* scores  = outMain + 256*512;         // (1,512,512)

  char* ws = (char*)d_ws;
  unsigned* wsMin  = (unsigned*)ws;
  unsigned* wsFlag = wsMin + 1;
  unsigned short* Ab    = (unsigned short*)(ws + 1024);     // 128KB A frag-linear
  float*          Up    = (float*)(ws + 132096);            // 512x256 f32
  float*          VmT   = (float*)(ws + 656384);            // 512x256 f32 [k][e]
  unsigned short* srcbf = (unsigned short*)(ws + 1180672);  // 256x512 bf16 [d][k]
  unsigned short* srcT  = (unsigned short*)(ws + 1442816);  // 512x256 bf16 [k][c]
  unsigned short* mW1b  = (unsigned short*)(ws + 1704960);  // 512x512 bf16
  unsigned short* mW2b  = (unsigned short*)(ws + 2229248);  // 256x512 bf16
  unsigned short* aW1A  = (unsigned short*)(ws + 2491392);  // 256x256 bf16
  unsigned short* aW1B  = (unsigned short*)(ws + 2622464);  // 256x256 bf16
  unsigned short* catT  = (unsigned short*)(ws + 2753536);  // 512x512 bf16 [q][c]
  unsigned short* prob  = (unsigned short*)(ws + 3277824);  // 512x512 bf16 [q][k]
  unsigned short* h2T   = (unsigned short*)(ws + 3802112);  // 512x512 bf16 [q][o]

  hipLaunchKernelGGL(kprep, dim3(769), dim3(256), 0, stream,
                     (const unsigned*)mask, wsMin, wsFlag, aW1, source, x, mW1, mW2,
                     Ab, srcbf, mW1b, mW2b, aW1A, aW1B, catT, srcT);
  hipLaunchKernelGGL(kprep2, dim3(64), dim3(256), 0, stream,
                     catT, aW1A, ab1, Up, srcT, aW1B, VmT);
  hipLaunchKernelGGL(kscores3, dim3(1024), dim3(256), 0, stream,
                     dist, Ab, VmT, Up, aW2, ab2, scores, wsMin);
  hipLaunchKernelGGL(ksoftmax, dim3(512), dim3(256), 0, stream,
                     mask, wsMin, wsFlag, scores, prob);
  // msgT[q][d] = prob @ source^T  -> catT[:, 256:]
  hipLaunchKernelGGL((gemm_k<1, 16>), dim3(32), dim3(256), 0, stream,
                     prob, 512, srcbf, 512, (const float*)nullptr, (void*)(catT + 256), 512, 4);
  // h2T[q][o] = relu(catT @ mW1^T + mb1)
  hipLaunchKernelGGL((gemm_k<7, 16>), dim3(64), dim3(256), 0, stream,
                     catT, 512, mW1b, 512, mb1, (void*)h2T, 512, 8);
  // out[o2][q] = mW2 @ h2 + mb2
  hipLaunchKernelGGL((gemm_k<8, 16>), dim3(32), dim3(256), 0, stream,
                     mW2b, 512, h2T, 512, mb2, (void*)outMain, 512, 8);
}